// Round 4
// baseline (136.039 us; speedup 1.0000x reference)
//
#include <hip/hip_runtime.h>

// StructureTensorEffect: B=4, C=3, H=W=1024, fp32.
// Round 4: 2 columns/thread sharing one contiguous window (float2 loads:
// VMEM/px 30 -> ~9), vertical streaming ROWS=4, row/col addresses clamped.
// Wrong-by-construction border pixels (y<=ip, x<=ip, x>=1023-ip) are
// store-masked in the fast path and written by a concurrent border slice
// (gridDim.y extra slice) using the verified slow_pixel. Bottom/right
// borders auto-correct under clamped loads (taps collapse, fm+fp=1).

#define W_ 1024
#define H_ 1024
#define PLANE (1 << 20)
#define ROWS 4

__device__ __forceinline__ float lerp1(float a, float b, float f) {
    return fmaf(f, b - a, a);
}

// Exact per-pixel reference path (any sigma, any border) — verified R1-R3.
__device__ void slow_pixel(const float* __restrict__ Xb, float* __restrict__ Ob,
                           float sg, int xi, int y)
{
    float imf = floorf(-sg), ipf = floorf(sg);
    float fm  = -sg - imf;
    float fp  =  sg - ipf;
    int   im  = (int)imf, ip = (int)ipf;

    int cm0 = min(max(xi + im, 0), W_ - 1), cm1 = min(cm0 + 1, W_ - 1);
    int cp0 = min(max(xi + ip, 0), W_ - 1), cp1 = min(cp0 + 1, W_ - 1);
    int rm0 = min(max(y + im, 0), H_ - 1),  rm1 = min(rm0 + 1, H_ - 1);
    int rp0 = min(max(y + ip, 0), H_ - 1),  rp1 = min(rp0 + 1, H_ - 1);

    int o_rm0 = rm0 << 10, o_rm1 = rm1 << 10;
    int o_rp0 = rp0 << 10, o_rp1 = rp1 << 10;
    int o_r0  = y   << 10;

    float oxx = 0.f, oyy = 0.f, oxy = 0.f;

    #pragma unroll
    for (int c = 0; c < 3; ++c) {
        const float* base = Xb + ((size_t)c << 20);

        float hm_m0 = lerp1(base[o_rm0 + cm0], base[o_rm0 + cm1], fm);
        float hm_m1 = lerp1(base[o_rm1 + cm0], base[o_rm1 + cm1], fm);
        float hm_0  = lerp1(base[o_r0  + cm0], base[o_r0  + cm1], fm);
        float hm_p0 = lerp1(base[o_rp0 + cm0], base[o_rp0 + cm1], fm);
        float hm_p1 = lerp1(base[o_rp1 + cm0], base[o_rp1 + cm1], fm);
        float hp_m0 = lerp1(base[o_rm0 + cp0], base[o_rm0 + cp1], fp);
        float hp_m1 = lerp1(base[o_rm1 + cp0], base[o_rm1 + cp1], fp);
        float hp_0  = lerp1(base[o_r0  + cp0], base[o_r0  + cp1], fp);
        float hp_p0 = lerp1(base[o_rp0 + cp0], base[o_rp0 + cp1], fp);
        float hp_p1 = lerp1(base[o_rp1 + cp0], base[o_rp1 + cp1], fp);
        float h0_m0 = base[o_rm0 + xi], h0_m1 = base[o_rm1 + xi];
        float h0_p0 = base[o_rp0 + xi], h0_p1 = base[o_rp1 + xi];

        float t0 = lerp1(hm_m0, hm_m1, fm);
        float t1 = hm_0;
        float t2 = lerp1(hm_p0, hm_p1, fp);
        float t3 = lerp1(h0_m0, h0_m1, fm);
        float t4 = lerp1(h0_p0, h0_p1, fp);
        float t5 = lerp1(hp_m0, hp_m1, fm);
        float t6 = hp_0;
        float t7 = lerp1(hp_p0, hp_p1, fp);

        float su = 0.25f * (t5 + t7 - t0 - t2) + 0.5f * (t6 - t1);
        float sv = 0.25f * (t2 + t7 - t0 - t5) + 0.5f * (t4 - t3);

        float l2 = (c == 0) ? 10000.f : 1.f;
        oxx = fmaf(l2 * su, su, oxx);
        oyy = fmaf(l2 * sv, sv, oyy);
        oxy = fmaf(l2 * su, sv, oxy);
    }

    int pix = (y << 10) | xi;
    Ob[pix]             = oxx;
    Ob[PLANE + pix]     = oyy;
    Ob[2 * PLANE + pix] = oxy;
}

template<int N>
__device__ __forceinline__ void acc(float (&arr)[N], int k, float val) {
    if (k >= 0 && k < N) arr[k] += val;   // k is constant after unroll
}

// Fast path: 2 columns (x, x+1; x even) x ROWS rows per thread.
// Window cols x-IP-1 .. x+IP+2 loaded as aligned float2 groups with
// clamped bases; row addresses clamped. Valid for all interior pixels;
// stores masked where the clamped construction deviates from reference
// (y <= IP, x <= IP, x >= W-1-IP); those come from the border slice.
template<int IP>
__device__ void fast2(const float* __restrict__ Xb, float* __restrict__ Ob,
                      float fp, float fm, int x, int y0)
{
    constexpr int RW   = ROWS + 2 * IP + 2;
    constexpr int OFFS = (IP == 2) ? 4 : 2;   // window start = x - OFFS (even)
    constexpr int NW2  = (IP == 2) ? 5 : 3;   // float2 groups
    constexpr int NW   = 2 * NW2;
    constexpr int E0   = (IP == 1) ? 0 : 1;   // hm tap base elem (col j-IP-1)
    constexpr int E1   = IP + OFFS;           // hp tap base elem (col j+IP)
    constexpr int EC   = OFFS;                // center elem (col j)

    int goff[NW2];
    #pragma unroll
    for (int g = 0; g < NW2; ++g)
        goff[g] = min(max(x - OFFS + 2 * g, 0), W_ - 2);

    int rown[RW];
    #pragma unroll
    for (int w = 0; w < RW; ++w)
        rown[w] = min(max(y0 - IP - 1 + w, 0), H_ - 1) << 10;

    float oxx0[ROWS], oyy0[ROWS], oxy0[ROWS];
    float oxx1[ROWS], oyy1[ROWS], oxy1[ROWS];
    #pragma unroll
    for (int k = 0; k < ROWS; ++k) {
        oxx0[k] = 0.f; oyy0[k] = 0.f; oxy0[k] = 0.f;
        oxx1[k] = 0.f; oyy1[k] = 0.f; oxy1[k] = 0.f;
    }

    #pragma unroll
    for (int c = 0; c < 3; ++c) {
        const float* base = Xb + ((size_t)c << 20);
        float su0[ROWS], sv0[ROWS], su1[ROWS], sv1[ROWS];
        #pragma unroll
        for (int k = 0; k < ROWS; ++k) {
            su0[k] = 0.f; sv0[k] = 0.f; su1[k] = 0.f; sv1[k] = 0.f;
        }

        #pragma unroll
        for (int w = 0; w < RW; ++w) {
            const float* rp = base + rown[w];
            float wv[NW];
            #pragma unroll
            for (int g = 0; g < NW2; ++g) {
                float2 L = *reinterpret_cast<const float2*>(rp + goff[g]);
                wv[2 * g]     = L.x;
                wv[2 * g + 1] = L.y;
            }

            float hm0 = lerp1(wv[E0],     wv[E0 + 1], fm);
            float hm1 = lerp1(wv[E0 + 1], wv[E0 + 2], fm);
            float hp0 = lerp1(wv[E1],     wv[E1 + 1], fp);
            float hp1 = lerp1(wv[E1 + 1], wv[E1 + 2], fp);
            float cc0 = wv[EC], cc1 = wv[EC + 1];

            float q0  = hp0 - hm0,      q1  = hp1 - hm1;
            float A0  = 0.25f * q0,     A1  = 0.25f * q1;
            float hq0 = 0.5f  * q0,     hq1 = 0.5f  * q1;
            float B0  = fmaf(0.25f, hm0 + hp0, 0.5f * cc0);
            float B1  = fmaf(0.25f, hm1 + hp1, 0.5f * cc1);
            float fpA0 = fp * A0, fmA0 = fm * A0, fpB0 = fp * B0, fmB0 = fm * B0;
            float fpA1 = fp * A1, fmA1 = fm * A1, fpB1 = fp * B1, fmB1 = fm * B1;

            acc(su0, w,              fpA0);  acc(su1, w,              fpA1);
            acc(su0, w - 1,          fmA0);  acc(su1, w - 1,          fmA1);
            acc(su0, w - IP - 1,     hq0);   acc(su1, w - IP - 1,     hq1);
            acc(su0, w - 2*IP - 1,   fmA0);  acc(su1, w - 2*IP - 1,   fmA1);
            acc(su0, w - 2*IP - 2,   fpA0);  acc(su1, w - 2*IP - 2,   fpA1);
            acc(sv0, w,             -fpB0);  acc(sv1, w,             -fpB1);
            acc(sv0, w - 1,         -fmB0);  acc(sv1, w - 1,         -fmB1);
            acc(sv0, w - 2*IP - 1,   fmB0);  acc(sv1, w - 2*IP - 1,   fmB1);
            acc(sv0, w - 2*IP - 2,   fpB0);  acc(sv1, w - 2*IP - 2,   fpB1);
        }

        float l2 = (c == 0) ? 10000.f : 1.f;
        #pragma unroll
        for (int k = 0; k < ROWS; ++k) {
            oxx0[k] = fmaf(l2 * su0[k], su0[k], oxx0[k]);
            oyy0[k] = fmaf(l2 * sv0[k], sv0[k], oyy0[k]);
            oxy0[k] = fmaf(l2 * su0[k], sv0[k], oxy0[k]);
            oxx1[k] = fmaf(l2 * su1[k], su1[k], oxx1[k]);
            oyy1[k] = fmaf(l2 * sv1[k], sv1[k], oyy1[k]);
            oxy1[k] = fmaf(l2 * su1[k], sv1[k], oxy1[k]);
        }
    }

    bool okx0 = (x     > IP) && (x     < W_ - 1 - IP);
    bool okx1 = (x + 1 > IP) && (x + 1 < W_ - 1 - IP);
    #pragma unroll
    for (int k = 0; k < ROWS; ++k) {
        if (y0 + k > IP) {
            int pix = ((y0 + k) << 10) | x;
            if (okx0 && okx1) {
                *reinterpret_cast<float2*>(Ob + pix)             = make_float2(oxx0[k], oxx1[k]);
                *reinterpret_cast<float2*>(Ob + PLANE + pix)     = make_float2(oyy0[k], oyy1[k]);
                *reinterpret_cast<float2*>(Ob + 2 * PLANE + pix) = make_float2(oxy0[k], oxy1[k]);
            } else {
                if (okx0) {
                    Ob[pix]             = oxx0[k];
                    Ob[PLANE + pix]     = oyy0[k];
                    Ob[2 * PLANE + pix] = oxy0[k];
                }
                if (okx1) {
                    Ob[pix + 1]             = oxx1[k];
                    Ob[PLANE + pix + 1]     = oyy1[k];
                    Ob[2 * PLANE + pix + 1] = oxy1[k];
                }
            }
        }
    }
}

// block (64,4): thread = 2 cols x 4 rows -> block tile 128x16.
// gridDim.y has one extra slice (index H_/16) doing border pixels.
__global__ __launch_bounds__(256) void st_kernel(
    const float* __restrict__ X, const float* __restrict__ S,
    float* __restrict__ O)
{
    int b  = blockIdx.z;
    const float* Xb = X + (size_t)b * 3 * PLANE;
    float*       Ob = O + (size_t)b * 3 * PLANE;
    float sg = S[b];

    if (blockIdx.y == (H_ / 16)) {
        // Border slice: worst-case region x in {0,1,2,1021,1022,1023} (all y)
        // plus y in {0,1,2} (all x). 9216 px over 2048 threads, 5 iters.
        int tid = blockIdx.x * 256 + threadIdx.y * 64 + threadIdx.x;
        #pragma unroll
        for (int it = 0; it < 5; ++it) {
            int pidx = tid + it * 2048;
            if (pidx < 6144) {
                int yy = pidx / 6;
                int cc = pidx - yy * 6;
                int xx = (cc < 3) ? cc : (W_ - 6 + cc);
                slow_pixel(Xb, Ob, sg, xx, yy);
            } else if (pidx < 9216) {
                int p2 = pidx - 6144;
                slow_pixel(Xb, Ob, sg, p2 & 1023, p2 >> 10);
            }
        }
        return;
    }

    int x  = blockIdx.x * 128 + threadIdx.x * 2;
    int y0 = blockIdx.y * 16 + threadIdx.y * ROWS;

    int ipv = (int)floorf(sg);
    int imv = (int)floorf(-sg);
    bool sig_ok = (imv == -ipv - 1) && ipv >= 0 && ipv <= 2;
    float fp = sg - (float)ipv;
    float fm = 1.0f - fp;

    if (sig_ok) {
        switch (ipv) {
            case 0:  fast2<0>(Xb, Ob, fp, fm, x, y0); break;
            case 1:  fast2<1>(Xb, Ob, fp, fm, x, y0); break;
            default: fast2<2>(Xb, Ob, fp, fm, x, y0); break;
        }
    } else {
        for (int k = 0; k < ROWS; ++k) {
            slow_pixel(Xb, Ob, sg, x,     y0 + k);
            slow_pixel(Xb, Ob, sg, x + 1, y0 + k);
        }
    }
}

extern "C" void kernel_launch(void* const* d_in, const int* in_sizes, int n_in,
                              void* d_out, int out_size, void* d_ws, size_t ws_size,
                              hipStream_t stream) {
    const float* x     = (const float*)d_in[0];
    const float* sigma = (const float*)d_in[1];
    float* out = (float*)d_out;

    dim3 grid(W_ / 128, H_ / 16 + 1, 4), block(64, 4);
    hipLaunchKernelGGL(st_kernel, grid, block, 0, stream, x, sigma, out);
}